// Round 11
// baseline (218.640 us; speedup 1.0000x reference)
//
#include <hip/hip_runtime.h>
#include <hip/hip_fp16.h>
#include <hip/hip_cooperative_groups.h>
#include <cstddef>

namespace cg = cooperative_groups;

#define B_   8
#define H_   96
#define W_   96
#define HW_  9216
#define PIX_ 73728

// LDS window geometry: rows hr-2..hr+4 (7), cols wc-3..wc+34 (38)
#define NWR    7
#define NWC    38
#define WINPX  266
#define NSLOTS 19

typedef __attribute__((ext_vector_type(8))) _Float16 halfx8;
typedef __attribute__((ext_vector_type(2))) __fp16 fp16x2_raw;
typedef __attribute__((ext_vector_type(4))) float floatx4;

// ws layout (byte offsets)
#define XT_OFF   0                          // fp16 NHWC x: PIX*64*2
#define WFM_OFF  (XT_OFF + PIX_*64*2)       // main W frags: 18*4*64*8 fp16
#define WFO_OFF  (WFM_OFF + 18*4*64*8*2)    // offs W frags: 18*2*64*8 fp16
#define WZ_OFF   (WFO_OFF + 18*2*64*8*2)    // 128B zero page

__device__ __forceinline__ unsigned pk2h(float a, float b) {
    fp16x2_raw h = __builtin_amdgcn_cvt_pkrtz(a, b);
    union { fp16x2_raw h2; unsigned u; } t; t.h2 = h; return t.u;
}
__device__ __forceinline__ halfx8 uph8(uint4 u) {
    union { uint4 u4; halfx8 h; } t; t.u4 = u; return t.h;
}
__device__ __forceinline__ halfx8 splat8(unsigned d) {
    union { unsigned u[4]; halfx8 h; } t;
    t.u[0] = d; t.u[1] = d; t.u[2] = d; t.u[3] = d; return t.h;
}
__device__ __forceinline__ void async_ld16(const void* g, void* l) {
    __builtin_amdgcn_global_load_lds((const __attribute__((address_space(1))) void*)g,
                                     (__attribute__((address_space(3))) void*)l,
                                     16, 0, 0);
}

// ===========================================================================
// Shared device body: weight prep item
__device__ __forceinline__ void prep_weight_item(int g,
                                                 const float* __restrict__ offw,
                                                 const float* __restrict__ mw,
                                                 const float* __restrict__ convw,
                                                 unsigned short* __restrict__ wfm,
                                                 unsigned short* __restrict__ wfo) {
    if (g < 4608) {
        int lane = g & 63, mtks = g >> 6;
        int mt = mtks & 3, ks = mtks >> 2;
        int o = mt * 16 + (lane & 15), quad = lane >> 4;
        float v[8];
        #pragma unroll
        for (int j = 0; j < 8; ++j) {
            int k = ks * 32 + quad * 8 + j;
            int t = k / 64, c = k % 64;
            v[j] = convw[(size_t)(o * 64 + c) * 9 + t];
        }
        uint4 pk;
        pk.x = pk2h(v[0], v[1]); pk.y = pk2h(v[2], v[3]);
        pk.z = pk2h(v[4], v[5]); pk.w = pk2h(v[6], v[7]);
        *(uint4*)(wfm + (size_t)g * 8) = pk;
    } else if (g < 4608 + 2304) {
        int g2 = g - 4608;
        int lane = g2 & 63, mtks = g2 >> 6;
        int mt = mtks & 1, ks = mtks >> 1;
        int m = mt * 16 + (lane & 15), quad = lane >> 4;
        float v[8];
        #pragma unroll
        for (int j = 0; j < 8; ++j) {
            int k = ks * 32 + quad * 8 + j;
            int t = k / 64, c = k % 64;
            float f = 0.f;
            if (m < 18)      f = offw[(size_t)(m * 64 + c) * 9 + t];
            else if (m < 27) f = mw[(size_t)((m - 18) * 64 + c) * 9 + t];
            v[j] = f;
        }
        uint4 pk;
        pk.x = pk2h(v[0], v[1]); pk.y = pk2h(v[2], v[3]);
        pk.z = pk2h(v[4], v[5]); pk.w = pk2h(v[6], v[7]);
        *(uint4*)(wfo + (size_t)g2 * 8) = pk;
    }
}

// ===========================================================================
// The deformable-conv block body (phases: stage window -> p1 -> p2 -> p3).
// Used by both the cooperative kernel and the fallback k_fused.
__device__ __forceinline__ void deform_body(unsigned char* s_win, unsigned char* s_u,
                                            int* s_cnt_p,
                                            int tid, int bb, int hr, int wc,
                                            const unsigned short* __restrict__ xtb,
                                            const unsigned short* __restrict__ wfo,
                                            const unsigned short* __restrict__ wfm,
                                            const float* __restrict__ offb,
                                            const float* __restrict__ mb,
                                            const float* __restrict__ convb,
                                            const unsigned short* __restrict__ wz,
                                            float* __restrict__ out) {
    float* s_off = (float*)s_u;
    unsigned char* s_meta = s_u;
    int w = tid >> 6, lane = tid & 63, col = lane & 15, quad = lane >> 4;

    // ---- stage window: direct-to-LDS DMA, source pre-swizzled; OOB -> zeros ----
    {
        int p0  = lane >> 3;
        int cgx = (lane & 7) ^ p0;
        const unsigned short* wzp = wz + cgx * 8;
        for (int i = w; i < 34; i += 6) {
            int p = i * 8 + p0;
            int wr = p / NWC, wcl = p - wr * NWC;
            int gr = hr - 2 + wr, gc = wc - 3 + wcl;
            bool ok = (p < WINPX) && ((unsigned)gr < 96u) && ((unsigned)gc < 96u);
            const unsigned short* src = ok ? (xtb + ((size_t)(gr * 96 + gc) * 64 + cgx * 8)) : wzp;
            async_ld16(src, s_win + i * 1024);
        }
    }
    __syncthreads();

    // ---- phase 1: offset/mod conv GEMM ----
    floatx4 aoff0 = (floatx4){0.f, 0.f, 0.f, 0.f};
    floatx4 aoff1 = (floatx4){0.f, 0.f, 0.f, 0.f};
    {
        int wr_base = 2 + (w >> 1);
        int wc_base = 3 + (w & 1) * 16 + col;
        #pragma unroll
        for (int t = 0; t < 9; ++t) {
            int dh = t / 3 - 1, dw = t % 3 - 1;
            int p = (wr_base + dh) * NWC + (wc_base + dw);
            int pb = p << 7, psw = (p & 7) << 4;
            #pragma unroll
            for (int ksl = 0; ksl < 2; ++ksl) {
                int ks = t * 2 + ksl;
                halfx8 a0 = *(const halfx8*)(wfo + ((size_t)(ks * 2 + 0) * 64 + lane) * 8);
                halfx8 a1 = *(const halfx8*)(wfo + ((size_t)(ks * 2 + 1) * 64 + lane) * 8);
                uint4 bvu = *(const uint4*)(s_win + pb + ((quad * 16 + ksl * 64) ^ psw));
                halfx8 bv = uph8(bvu);
                aoff0 = __builtin_amdgcn_mfma_f32_16x16x32_f16(a0, bv, aoff0, 0, 0, 0);
                aoff1 = __builtin_amdgcn_mfma_f32_16x16x32_f16(a1, bv, aoff1, 0, 0, 0);
            }
        }
    }
    #pragma unroll
    for (int r = 0; r < 4; ++r) {
        s_off[(quad * 4 + r) * 98 + (w * 16 + col)] = aoff0[r];
        int m = 16 + quad * 4 + r;
        if (m < 27) s_off[m * 98 + (w * 16 + col)] = aoff1[r];
    }
    __syncthreads();

    // ---- phase 2a: read s_off (+bias) into static registers (864 items) ----
    float ox0, oy0, mv0, ox1, oy1, mv1, ox2 = 0.f, oy2 = 0.f, mv2 = 0.f;
    bool has2 = tid < 96;
    {
        int px = tid % 96, n = tid / 96;
        ox0 = s_off[n * 98 + px]        + offb[n];
        oy0 = s_off[(9 + n) * 98 + px]  + offb[9 + n];
        mv0 = s_off[(18 + n) * 98 + px] + mb[n];
    }
    {
        int id = tid + 384;
        int px = id % 96, n = id / 96;
        ox1 = s_off[n * 98 + px]        + offb[n];
        oy1 = s_off[(9 + n) * 98 + px]  + offb[9 + n];
        mv1 = s_off[(18 + n) * 98 + px] + mb[n];
    }
    if (has2) {
        int id = tid + 768;
        int px = id % 96, n = id / 96;
        ox2 = s_off[n * 98 + px]        + offb[n];
        oy2 = s_off[(9 + n) * 98 + px]  + offb[9 + n];
        mv2 = s_off[(18 + n) * 98 + px] + mb[n];
    }
    __syncthreads();

    // ---- phase 2b: bilinear metadata ----
    auto meta_one = [&](int id, float ox, float oy, float mv) {
        int px = id % 96, n = id / 96;
        float modv = 1.f / (1.f + __expf(-mv));
        int prow = hr + (px >> 5), pcol = wc + (px & 31);
        float pxx = ox + (float)(prow + 1) + (float)(n / 3 - 1);
        float pyy = oy + (float)(pcol + 1) + (float)(n % 3 - 1);
        float flx = floorf(pxx), fly = floorf(pyy);
        float tlxf = fminf(fmaxf(flx,       0.f), 97.f);
        float tlyf = fminf(fmaxf(fly,       0.f), 97.f);
        float brxf = fminf(fmaxf(flx + 1.f, 0.f), 97.f);
        float bryf = fminf(fmaxf(fly + 1.f, 0.f), 97.f);
        float pcx  = fminf(fmaxf(pxx, 0.f), 97.f);
        float pcy  = fminf(fmaxf(pyy, 0.f), 97.f);
        float gx0 = 1.f + tlxf - pcx;
        float gx1 = 1.f - (brxf - pcx);
        float gy0 = 1.f + tlyf - pcy;
        float gy1 = 1.f - (bryf - pcy);
        int tlx = (int)tlxf, tly = (int)tlyf, brx = (int)brxf, bry = (int)bryf;
        int   qxs[4] = {tlx, tlx, brx, brx};
        int   qys[4] = {tly, bry, tly, bry};
        float gs4[4] = {gx0 * gy0, gx0 * gy1, gx1 * gy0, gx1 * gy1};
        unsigned short si[4]; unsigned short hg[4];
        #pragma unroll
        for (int c4 = 0; c4 < 4; ++c4) {
            int qx = qxs[c4], qy = qys[c4];
            bool valid = (qx >= 1) && (qx <= 96) && (qy >= 1) && (qy <= 96);
            int gr = qx - 1, gc = qy - 1;
            int wr = gr - (hr - 2), wcl = gc - (wc - 3);
            bool inwin = ((unsigned)wr < (unsigned)NWR) && ((unsigned)wcl < (unsigned)NWC);
            unsigned short idxv; float gvf;
            if (inwin) {
                idxv = (unsigned short)(wr * NWC + wcl);
                gvf = gs4[c4] * modv;
            } else if (!valid) {
                idxv = 0; gvf = 0.f;
            } else {
                int s = atomicAdd(s_cnt_p, 1);
                int gidx = gr * 96 + gc;
                if (s < NSLOTS) {
                    int ps = WINPX + s;
                    #pragma unroll
                    for (int ch = 0; ch < 8; ++ch) {
                        uint4 v = *(const uint4*)(xtb + (size_t)gidx * 64 + ch * 8);
                        *(uint4*)(s_win + (size_t)ps * 128 + ((ch ^ (ps & 7)) * 16)) = v;
                    }
                    idxv = (unsigned short)ps;
                } else {
                    idxv = (unsigned short)(0x8000u | (unsigned)gidx);
                }
                gvf = gs4[c4] * modv;
            }
            si[c4] = idxv;
            hg[c4] = __half_as_ushort(__float2half_rn(gvf));
        }
        uint4 mw4;
        mw4.x = si[0] | ((unsigned)si[1] << 16);
        mw4.y = si[2] | ((unsigned)si[3] << 16);
        mw4.z = hg[0] | ((unsigned)hg[1] << 16);
        mw4.w = hg[2] | ((unsigned)hg[3] << 16);
        *(uint4*)(s_meta + ((size_t)px * 9 + n) * 16) = mw4;
    };
    meta_one(tid,       ox0, oy0, mv0);
    meta_one(tid + 384, ox1, oy1, mv1);
    if (has2) meta_one(tid + 768, ox2, oy2, mv2);
    __syncthreads();

    // ---- phase 3: wave = 16 px x 64 o-channels ----
    int px3 = w * 16 + col;
    floatx4 acc[4];
    #pragma unroll
    for (int mt = 0; mt < 4; ++mt) acc[mt] = (floatx4){0.f, 0.f, 0.f, 0.f};

    int qk0 = quad * 16, qk1 = quad * 16 + 64;

    #pragma unroll
    for (int n = 0; n < 9; ++n) {
        uint4 mu = *(const uint4*)(s_meta + ((size_t)px3 * 9 + n) * 16);
        unsigned i0 = mu.x & 0xFFFFu, i1 = mu.x >> 16;
        unsigned i2 = mu.y & 0xFFFFu, i3 = mu.y >> 16;
        int pm0 = (i0 & 0x8000u) ? 0 : (int)i0;
        int pm1 = (i1 & 0x8000u) ? 0 : (int)i1;
        int pm2 = (i2 & 0x8000u) ? 0 : (int)i2;
        int pm3 = (i3 & 0x8000u) ? 0 : (int)i3;
        int b0 = pm0 << 7, s0 = (pm0 & 7) << 4;
        int b1 = pm1 << 7, s1 = (pm1 & 7) << 4;
        int b2 = pm2 << 7, s2 = (pm2 & 7) << 4;
        int b3 = pm3 << 7, s3 = (pm3 & 7) << 4;
        uint4 cA0 = *(const uint4*)(s_win + b0 + (qk0 ^ s0));
        uint4 cA1 = *(const uint4*)(s_win + b1 + (qk0 ^ s1));
        uint4 cA2 = *(const uint4*)(s_win + b2 + (qk0 ^ s2));
        uint4 cA3 = *(const uint4*)(s_win + b3 + (qk0 ^ s3));
        uint4 cB0 = *(const uint4*)(s_win + b0 + (qk1 ^ s0));
        uint4 cB1 = *(const uint4*)(s_win + b1 + (qk1 ^ s1));
        uint4 cB2 = *(const uint4*)(s_win + b2 + (qk1 ^ s2));
        uint4 cB3 = *(const uint4*)(s_win + b3 + (qk1 ^ s3));
        if (__any((int)((i0 | i1 | i2 | i3) & 0x8000u))) {
            if (i0 & 0x8000u) { size_t ga = (size_t)(i0 & 0x3FFFu) * 64 + quad * 8;
                cA0 = *(const uint4*)(xtb + ga); cB0 = *(const uint4*)(xtb + ga + 32); }
            if (i1 & 0x8000u) { size_t ga = (size_t)(i1 & 0x3FFFu) * 64 + quad * 8;
                cA1 = *(const uint4*)(xtb + ga); cB1 = *(const uint4*)(xtb + ga + 32); }
            if (i2 & 0x8000u) { size_t ga = (size_t)(i2 & 0x3FFFu) * 64 + quad * 8;
                cA2 = *(const uint4*)(xtb + ga); cB2 = *(const uint4*)(xtb + ga + 32); }
            if (i3 & 0x8000u) { size_t ga = (size_t)(i3 & 0x3FFFu) * 64 + quad * 8;
                cA3 = *(const uint4*)(xtb + ga); cB3 = *(const uint4*)(xtb + ga + 32); }
        }
        unsigned gl0 = (mu.z & 0xFFFFu) | (mu.z << 16);
        unsigned gl1 = (mu.z >> 16) | (mu.z & 0xFFFF0000u);
        unsigned gl2 = (mu.w & 0xFFFFu) | (mu.w << 16);
        unsigned gl3 = (mu.w >> 16) | (mu.w & 0xFFFF0000u);
        halfx8 g0 = splat8(gl0), g1 = splat8(gl1), g2 = splat8(gl2), g3 = splat8(gl3);
        halfx8 vA = uph8(cA0) * g0;
        vA += uph8(cA1) * g1; vA += uph8(cA2) * g2; vA += uph8(cA3) * g3;
        halfx8 vB = uph8(cB0) * g0;
        vB += uph8(cB1) * g1; vB += uph8(cB2) * g2; vB += uph8(cB3) * g3;
        #pragma unroll
        for (int mt = 0; mt < 4; ++mt) {
            halfx8 afA = *(const halfx8*)(wfm + ((size_t)((n * 2 + 0) * 4 + mt) * 64 + lane) * 8);
            halfx8 afB = *(const halfx8*)(wfm + ((size_t)((n * 2 + 1) * 4 + mt) * 64 + lane) * 8);
            acc[mt] = __builtin_amdgcn_mfma_f32_16x16x32_f16(afA, vA, acc[mt], 0, 0, 0);
            acc[mt] = __builtin_amdgcn_mfma_f32_16x16x32_f16(afB, vB, acc[mt], 0, 0, 0);
        }
    }

    // ---- epilogue ----
    int sp = (hr + (w >> 1)) * 96 + wc + (w & 1) * 16 + col;
    #pragma unroll
    for (int mt = 0; mt < 4; ++mt) {
        float4 cb4 = *(const float4*)&convb[mt * 16 + quad * 4];
        #pragma unroll
        for (int r = 0; r < 4; ++r) {
            int o = mt * 16 + quad * 4 + r;
            float bias = (r == 0) ? cb4.x : (r == 1) ? cb4.y : (r == 2) ? cb4.z : cb4.w;
            out[(size_t)(bb * 64 + o) * HW_ + sp] = acc[mt][r] + bias;
        }
    }
}

// ===========================================================================
// Cooperative single kernel. __launch_bounds__(384, 5): VGPR capped so
// 5 waves/EU (20 waves/CU) fit -> 3 blocks/CU co-resident -> 768 blocks OK.
__global__ __launch_bounds__(384, 5) void k_all(const float* __restrict__ x,
                                                unsigned short* __restrict__ xt,
                                                const float* __restrict__ offw,
                                                const float* __restrict__ mw,
                                                const float* __restrict__ convw,
                                                unsigned short* __restrict__ wfm,
                                                unsigned short* __restrict__ wfo,
                                                const float* __restrict__ offb,
                                                const float* __restrict__ mb,
                                                const float* __restrict__ convb,
                                                unsigned short* __restrict__ wz,
                                                float* __restrict__ out) {
    __shared__ __align__(16) unsigned char s_win[(WINPX + NSLOTS) * 128];  // 36480 B
    __shared__ __align__(16) unsigned char s_u[96 * 9 * 16];               // 13824 B
    __shared__ int s_cnt;

    cg::grid_group grid = cg::this_grid();
    int tid = threadIdx.x;
    int blk = (blockIdx.x & 7) * 96 + (blockIdx.x >> 3);   // XCD swizzle (768 = 8x96)
    int bb  = blk / 96;
    int rem = blk % 96;
    int hr  = (rem / 3) * 3;
    int wc  = (rem % 3) * 32;
    const unsigned short* xtb = xt + (size_t)bb * HW_ * 64;
    if (tid == 0) s_cnt = 0;

    // ---- phase T: transpose own 96-px tile, f32 NCHW -> fp16 NHWC ----
    {
        float* tf = (float*)s_win;      // [64][97] f32, aliases s_win
        #pragma unroll
        for (int it = 0; it < 4; ++it) {
            int task = it * 384 + tid;
            int o = task * 4;
            int c = o / 96, p = o - c * 96;
            int pr = p >> 5, pc = p & 31;
            float4 v = *(const float4*)&x[(size_t)(bb * 64 + c) * HW_ + (hr + pr) * 96 + wc + pc];
            tf[c * 97 + p + 0] = v.x;
            tf[c * 97 + p + 1] = v.y;
            tf[c * 97 + p + 2] = v.z;
            tf[c * 97 + p + 3] = v.w;
        }
        if (blockIdx.x < 18) prep_weight_item(blockIdx.x * 384 + tid, offw, mw, convw, wfm, wfo);
        if (blockIdx.x == 18 && tid < 8) {
            uint4 z = make_uint4(0, 0, 0, 0);
            *(uint4*)(wz + (size_t)tid * 8) = z;
        }
        __syncthreads();
        #pragma unroll
        for (int it = 0; it < 2; ++it) {
            int task = it * 384 + tid;
            int px = task >> 3, cgp = task & 7;
            uint4 pk;
            pk.x = pk2h(tf[(cgp * 8 + 0) * 97 + px], tf[(cgp * 8 + 1) * 97 + px]);
            pk.y = pk2h(tf[(cgp * 8 + 2) * 97 + px], tf[(cgp * 8 + 3) * 97 + px]);
            pk.z = pk2h(tf[(cgp * 8 + 4) * 97 + px], tf[(cgp * 8 + 5) * 97 + px]);
            pk.w = pk2h(tf[(cgp * 8 + 6) * 97 + px], tf[(cgp * 8 + 7) * 97 + px]);
            *(uint4*)(xt + ((size_t)(bb * HW_ + (hr + (px >> 5)) * 96 + wc + (px & 31))) * 64 + cgp * 8) = pk;
        }
    }
    grid.sync();

    deform_body(s_win, s_u, &s_cnt, tid, bb, hr, wc, xtb, wfo, wfm, offb, mb, convb, wz, out);
}

// ===========================================================================
// Fallback two-kernel path (R9, proven).
__global__ __launch_bounds__(256) void k_transpose(const float* __restrict__ x,
                                                   unsigned short* __restrict__ xt,
                                                   const float* __restrict__ offw,
                                                   const float* __restrict__ mw,
                                                   const float* __restrict__ convw,
                                                   unsigned short* __restrict__ wfm,
                                                   unsigned short* __restrict__ wfo,
                                                   unsigned short* __restrict__ wz) {
    if (blockIdx.x >= 1152) {
        int g = (blockIdx.x - 1152) * 256 + threadIdx.x;
        if (g < 6912) prep_weight_item(g, offw, mw, convw, wfm, wfo);
        else if (g < 6920) {
            uint4 z = make_uint4(0, 0, 0, 0);
            *(uint4*)(wz + (size_t)(g - 6912) * 8) = z;
        }
        return;
    }
    __shared__ float tile[64 * 65];
    int bb  = blockIdx.x / 144;
    int sp0 = (blockIdx.x % 144) * 64;
    int t = threadIdx.x;
    int s4 = (t & 15) * 4, cq = t >> 4;
    #pragma unroll
    for (int i = 0; i < 4; ++i) {
        int c = cq + 16 * i;
        float4 v = *(const float4*)&x[(size_t)(bb * 64 + c) * HW_ + sp0 + s4];
        tile[c * 65 + s4 + 0] = v.x;
        tile[c * 65 + s4 + 1] = v.y;
        tile[c * 65 + s4 + 2] = v.z;
        tile[c * 65 + s4 + 3] = v.w;
    }
    __syncthreads();
    int c8 = t & 7, sgrp = t >> 3;
    #pragma unroll
    for (int i = 0; i < 2; ++i) {
        int s2 = i * 32 + sgrp;
        uint4 pk;
        pk.x = pk2h(tile[(c8 * 8 + 0) * 65 + s2], tile[(c8 * 8 + 1) * 65 + s2]);
        pk.y = pk2h(tile[(c8 * 8 + 2) * 65 + s2], tile[(c8 * 8 + 3) * 65 + s2]);
        pk.z = pk2h(tile[(c8 * 8 + 4) * 65 + s2], tile[(c8 * 8 + 5) * 65 + s2]);
        pk.w = pk2h(tile[(c8 * 8 + 6) * 65 + s2], tile[(c8 * 8 + 7) * 65 + s2]);
        *(uint4*)(xt + (size_t)(bb * HW_ + sp0 + s2) * 64 + c8 * 8) = pk;
    }
}

__global__ __launch_bounds__(384, 5) void k_fused(const unsigned short* __restrict__ xt,
                                                  const unsigned short* __restrict__ wfo,
                                                  const unsigned short* __restrict__ wfm,
                                                  const float* __restrict__ offb,
                                                  const float* __restrict__ mb,
                                                  const float* __restrict__ convb,
                                                  const unsigned short* __restrict__ wz,
                                                  float* __restrict__ out) {
    __shared__ __align__(16) unsigned char s_win[(WINPX + NSLOTS) * 128];
    __shared__ __align__(16) unsigned char s_u[96 * 9 * 16];
    __shared__ int s_cnt;
    int tid = threadIdx.x;
    int blk = (blockIdx.x & 7) * 96 + (blockIdx.x >> 3);
    int bb  = blk / 96;
    int rem = blk % 96;
    int hr  = (rem / 3) * 3;
    int wc  = (rem % 3) * 32;
    const unsigned short* xtb = xt + (size_t)bb * HW_ * 64;
    if (tid == 0) s_cnt = 0;
    __syncthreads();
    deform_body(s_win, s_u, &s_cnt, tid, bb, hr, wc, xtb, wfo, wfm, offb, mb, convb, wz, out);
}

// ---------------------------------------------------------------------------
extern "C" void kernel_launch(void* const* d_in, const int* in_sizes, int n_in,
                              void* d_out, int out_size, void* d_ws, size_t ws_size,
                              hipStream_t stream) {
    const float* x     = (const float*)d_in[0];
    const float* offw  = (const float*)d_in[1];
    const float* offb  = (const float*)d_in[2];
    const float* mw    = (const float*)d_in[3];
    const float* mb    = (const float*)d_in[4];
    const float* convw = (const float*)d_in[5];
    const float* convb = (const float*)d_in[6];
    char* ws = (char*)d_ws;
    unsigned short* xt16 = (unsigned short*)(ws + XT_OFF);
    unsigned short* wfm  = (unsigned short*)(ws + WFM_OFF);
    unsigned short* wfo  = (unsigned short*)(ws + WFO_OFF);
    unsigned short* wz   = (unsigned short*)(ws + WZ_OFF);
    float* out = (float*)d_out;

    void* args[] = {(void*)&x, (void*)&xt16, (void*)&offw, (void*)&mw, (void*)&convw,
                    (void*)&wfm, (void*)&wfo, (void*)&offb, (void*)&mb, (void*)&convb,
                    (void*)&wz, (void*)&out};
    hipError_t e = hipLaunchCooperativeKernel((void*)k_all, dim3(768), dim3(384), args, 0, stream);
    if (e != hipSuccess) {
        // fallback: proven two-kernel path
        k_transpose<<<dim3(1152 + 28), dim3(256), 0, stream>>>(x, xt16, offw, mw, convw, wfm, wfo, wz);
        k_fused    <<<dim3(768),       dim3(384), 0, stream>>>(xt16, wfo, wfm, offb, mb, convb, wz, out);
    }
}

// Round 12
// 119.721 us; speedup vs baseline: 1.8262x; 1.8262x over previous
//
#include <hip/hip_runtime.h>
#include <hip/hip_fp16.h>
#include <cstddef>

#define B_   8
#define H_   96
#define W_   96
#define HW_  9216
#define PIX_ 73728

// LDS window geometry: rows hr-2..hr+4 (7), cols wc-3..wc+34 (38)
#define NWR    7
#define NWC    38
#define WINPX  266
#define NSLOTS 19

typedef __attribute__((ext_vector_type(8))) _Float16 halfx8;
typedef __attribute__((ext_vector_type(2))) __fp16 fp16x2_raw;
typedef __attribute__((ext_vector_type(4))) float floatx4;

// ws layout (byte offsets)
#define XT_OFF   0                          // fp16 NHWC x: PIX*64*2
#define WFM_OFF  (XT_OFF + PIX_*64*2)       // main W frags: 18*4*64*8 fp16
#define WFO_OFF  (WFM_OFF + 18*4*64*8*2)    // offs W frags: 18*2*64*8 fp16
#define WZ_OFF   (WFO_OFF + 18*2*64*8*2)    // 128B zero page

__device__ __forceinline__ unsigned pk2h(float a, float b) {
    fp16x2_raw h = __builtin_amdgcn_cvt_pkrtz(a, b);
    union { fp16x2_raw h2; unsigned u; } t; t.h2 = h; return t.u;
}
__device__ __forceinline__ halfx8 uph8(uint4 u) {
    union { uint4 u4; halfx8 h; } t; t.u4 = u; return t.h;
}
__device__ __forceinline__ halfx8 splat8(unsigned d) {
    union { unsigned u[4]; halfx8 h; } t;
    t.u[0] = d; t.u[1] = d; t.u[2] = d; t.u[3] = d; return t.h;
}
__device__ __forceinline__ void async_ld16(const void* g, void* l) {
    __builtin_amdgcn_global_load_lds((const __attribute__((address_space(1))) void*)g,
                                     (__attribute__((address_space(3))) void*)l,
                                     16, 0, 0);
}

// ---------------------------------------------------------------------------
// Weight prep item (shared helper)
__device__ __forceinline__ void prep_weight_item(int g,
                                                 const float* __restrict__ offw,
                                                 const float* __restrict__ mw,
                                                 const float* __restrict__ convw,
                                                 unsigned short* __restrict__ wfm,
                                                 unsigned short* __restrict__ wfo) {
    if (g < 4608) {
        int lane = g & 63, mtks = g >> 6;
        int mt = mtks & 3, ks = mtks >> 2;
        int o = mt * 16 + (lane & 15), quad = lane >> 4;
        float v[8];
        #pragma unroll
        for (int j = 0; j < 8; ++j) {
            int k = ks * 32 + quad * 8 + j;
            int t = k / 64, c = k % 64;
            v[j] = convw[(size_t)(o * 64 + c) * 9 + t];
        }
        uint4 pk;
        pk.x = pk2h(v[0], v[1]); pk.y = pk2h(v[2], v[3]);
        pk.z = pk2h(v[4], v[5]); pk.w = pk2h(v[6], v[7]);
        *(uint4*)(wfm + (size_t)g * 8) = pk;
    } else if (g < 4608 + 2304) {
        int g2 = g - 4608;
        int lane = g2 & 63, mtks = g2 >> 6;
        int mt = mtks & 1, ks = mtks >> 1;
        int m = mt * 16 + (lane & 15), quad = lane >> 4;
        float v[8];
        #pragma unroll
        for (int j = 0; j < 8; ++j) {
            int k = ks * 32 + quad * 8 + j;
            int t = k / 64, c = k % 64;
            float f = 0.f;
            if (m < 18)      f = offw[(size_t)(m * 64 + c) * 9 + t];
            else if (m < 27) f = mw[(size_t)((m - 18) * 64 + c) * 9 + t];
            v[j] = f;
        }
        uint4 pk;
        pk.x = pk2h(v[0], v[1]); pk.y = pk2h(v[2], v[3]);
        pk.z = pk2h(v[4], v[5]); pk.w = pk2h(v[6], v[7]);
        *(uint4*)(wfo + (size_t)g2 * 8) = pk;
    }
}

// ---------------------------------------------------------------------------
// NCHW f32 -> NHWC fp16 transpose via LDS tile; tail blocks pack weights.
__global__ __launch_bounds__(256) void k_transpose(const float* __restrict__ x,
                                                   unsigned short* __restrict__ xt,
                                                   const float* __restrict__ offw,
                                                   const float* __restrict__ mw,
                                                   const float* __restrict__ convw,
                                                   unsigned short* __restrict__ wfm,
                                                   unsigned short* __restrict__ wfo,
                                                   unsigned short* __restrict__ wz) {
    if (blockIdx.x >= 1152) {
        int g = (blockIdx.x - 1152) * 256 + threadIdx.x;
        if (g < 6912) prep_weight_item(g, offw, mw, convw, wfm, wfo);
        else if (g < 6920) {
            uint4 z = make_uint4(0, 0, 0, 0);
            *(uint4*)(wz + (size_t)(g - 6912) * 8) = z;
        }
        return;
    }
    __shared__ float tile[64 * 65];
    int bb  = blockIdx.x / 144;
    int sp0 = (blockIdx.x % 144) * 64;
    int t = threadIdx.x;
    int s4 = (t & 15) * 4, cq = t >> 4;
    #pragma unroll
    for (int i = 0; i < 4; ++i) {
        int c = cq + 16 * i;
        float4 v = *(const float4*)&x[(size_t)(bb * 64 + c) * HW_ + sp0 + s4];
        tile[c * 65 + s4 + 0] = v.x;
        tile[c * 65 + s4 + 1] = v.y;
        tile[c * 65 + s4 + 2] = v.z;
        tile[c * 65 + s4 + 3] = v.w;
    }
    __syncthreads();
    int c8 = t & 7, sgrp = t >> 3;
    #pragma unroll
    for (int i = 0; i < 2; ++i) {
        int s2 = i * 32 + sgrp;
        uint4 pk;
        pk.x = pk2h(tile[(c8 * 8 + 0) * 65 + s2], tile[(c8 * 8 + 1) * 65 + s2]);
        pk.y = pk2h(tile[(c8 * 8 + 2) * 65 + s2], tile[(c8 * 8 + 3) * 65 + s2]);
        pk.z = pk2h(tile[(c8 * 8 + 4) * 65 + s2], tile[(c8 * 8 + 5) * 65 + s2]);
        pk.w = pk2h(tile[(c8 * 8 + 6) * 65 + s2], tile[(c8 * 8 + 7) * 65 + s2]);
        *(uint4*)(xt + (size_t)(bb * HW_ + sp0 + s2) * 64 + c8 * 8) = pk;
    }
}

// ---------------------------------------------------------------------------
// Fused kernel (R9 structure, proven). Block = 384 thr = 6 waves, 96 px
// (3 rows x 32 cols). 768 blocks, 3/CU. 7x38 window DMA'd to LDS; s_off
// aliased onto s_meta; wave = 16 px x 64 o. + s_setprio around MFMA.
__global__ __launch_bounds__(384, 5) void k_fused(const unsigned short* __restrict__ xt,
                                                  const unsigned short* __restrict__ wfo,
                                                  const unsigned short* __restrict__ wfm,
                                                  const float* __restrict__ offb,
                                                  const float* __restrict__ mb,
                                                  const float* __restrict__ convb,
                                                  const unsigned short* __restrict__ wz,
                                                  float* __restrict__ out) {
    __shared__ __align__(16) unsigned char s_win[(WINPX + NSLOTS) * 128];  // 36480 B
    __shared__ __align__(16) unsigned char s_u[96 * 9 * 16];               // 13824 B union
    __shared__ int s_cnt;
    float* s_off = (float*)s_u;
    unsigned char* s_meta = s_u;

    int tid = threadIdx.x;
    int w = tid >> 6, lane = tid & 63, col = lane & 15, quad = lane >> 4;
    // XCD-aware swizzle: each XCD owns one batch region (768 = 8 x 96)
    int blk = (blockIdx.x & 7) * 96 + (blockIdx.x >> 3);
    int bb  = blk / 96;
    int rem = blk % 96;
    int hr  = (rem / 3) * 3;
    int wc  = (rem % 3) * 32;
    const unsigned short* xtb = xt + (size_t)bb * HW_ * 64;

    // ---- stage window: direct-to-LDS DMA, source pre-swizzled; OOB -> zeros ----
    if (tid == 0) s_cnt = 0;
    {
        int p0  = lane >> 3;
        int cgx = (lane & 7) ^ p0;
        const unsigned short* wzp = wz + cgx * 8;
        for (int i = w; i < 34; i += 6) {
            int p = i * 8 + p0;
            int wr = p / NWC, wcl = p - wr * NWC;
            int gr = hr - 2 + wr, gc = wc - 3 + wcl;
            bool ok = (p < WINPX) && ((unsigned)gr < 96u) && ((unsigned)gc < 96u);
            const unsigned short* src = ok ? (xtb + ((size_t)(gr * 96 + gc) * 64 + cgx * 8)) : wzp;
            async_ld16(src, s_win + i * 1024);
        }
    }
    __syncthreads();

    // ---- phase 1: offset/mod conv GEMM (B from LDS window) ----
    floatx4 aoff0 = (floatx4){0.f, 0.f, 0.f, 0.f};
    floatx4 aoff1 = (floatx4){0.f, 0.f, 0.f, 0.f};
    {
        int wr_base = 2 + (w >> 1);
        int wc_base = 3 + (w & 1) * 16 + col;
        #pragma unroll
        for (int t = 0; t < 9; ++t) {
            int dh = t / 3 - 1, dw = t % 3 - 1;
            int p = (wr_base + dh) * NWC + (wc_base + dw);
            int pb = p << 7, psw = (p & 7) << 4;
            #pragma unroll
            for (int ksl = 0; ksl < 2; ++ksl) {
                int ks = t * 2 + ksl;
                halfx8 a0 = *(const halfx8*)(wfo + ((size_t)(ks * 2 + 0) * 64 + lane) * 8);
                halfx8 a1 = *(const halfx8*)(wfo + ((size_t)(ks * 2 + 1) * 64 + lane) * 8);
                uint4 bvu = *(const uint4*)(s_win + pb + ((quad * 16 + ksl * 64) ^ psw));
                halfx8 bv = uph8(bvu);
                aoff0 = __builtin_amdgcn_mfma_f32_16x16x32_f16(a0, bv, aoff0, 0, 0, 0);
                aoff1 = __builtin_amdgcn_mfma_f32_16x16x32_f16(a1, bv, aoff1, 0, 0, 0);
            }
        }
    }
    #pragma unroll
    for (int r = 0; r < 4; ++r) {
        s_off[(quad * 4 + r) * 98 + (w * 16 + col)] = aoff0[r];
        int m = 16 + quad * 4 + r;
        if (m < 27) s_off[m * 98 + (w * 16 + col)] = aoff1[r];
    }
    __syncthreads();

    // ---- phase 2a: read s_off (+bias) into static registers (864 items) ----
    float ox0, oy0, mv0, ox1, oy1, mv1, ox2 = 0.f, oy2 = 0.f, mv2 = 0.f;
    bool has2 = tid < 96;
    {
        int px = tid % 96, n = tid / 96;
        ox0 = s_off[n * 98 + px]        + offb[n];
        oy0 = s_off[(9 + n) * 98 + px]  + offb[9 + n];
        mv0 = s_off[(18 + n) * 98 + px] + mb[n];
    }
    {
        int id = tid + 384;
        int px = id % 96, n = id / 96;
        ox1 = s_off[n * 98 + px]        + offb[n];
        oy1 = s_off[(9 + n) * 98 + px]  + offb[9 + n];
        mv1 = s_off[(18 + n) * 98 + px] + mb[n];
    }
    if (has2) {
        int id = tid + 768;
        int px = id % 96, n = id / 96;
        ox2 = s_off[n * 98 + px]        + offb[n];
        oy2 = s_off[(9 + n) * 98 + px]  + offb[9 + n];
        mv2 = s_off[(18 + n) * 98 + px] + mb[n];
    }
    __syncthreads();   // s_off fully read; s_u becomes s_meta

    // ---- phase 2b: bilinear metadata ----
    auto meta_one = [&](int id, float ox, float oy, float mv) {
        int px = id % 96, n = id / 96;
        float modv = 1.f / (1.f + __expf(-mv));
        int prow = hr + (px >> 5), pcol = wc + (px & 31);
        float pxx = ox + (float)(prow + 1) + (float)(n / 3 - 1);
        float pyy = oy + (float)(pcol + 1) + (float)(n % 3 - 1);
        float flx = floorf(pxx), fly = floorf(pyy);
        float tlxf = fminf(fmaxf(flx,       0.f), 97.f);
        float tlyf = fminf(fmaxf(fly,       0.f), 97.f);
        float brxf = fminf(fmaxf(flx + 1.f, 0.f), 97.f);
        float bryf = fminf(fmaxf(fly + 1.f, 0.f), 97.f);
        float pcx  = fminf(fmaxf(pxx, 0.f), 97.f);
        float pcy  = fminf(fmaxf(pyy, 0.f), 97.f);
        float gx0 = 1.f + tlxf - pcx;
        float gx1 = 1.f - (brxf - pcx);
        float gy0 = 1.f + tlyf - pcy;
        float gy1 = 1.f - (bryf - pcy);
        int tlx = (int)tlxf, tly = (int)tlyf, brx = (int)brxf, bry = (int)bryf;
        int   qxs[4] = {tlx, tlx, brx, brx};
        int   qys[4] = {tly, bry, tly, bry};
        float gs4[4] = {gx0 * gy0, gx0 * gy1, gx1 * gy0, gx1 * gy1};
        unsigned short si[4]; unsigned short hg[4];
        #pragma unroll
        for (int c4 = 0; c4 < 4; ++c4) {
            int qx = qxs[c4], qy = qys[c4];
            bool valid = (qx >= 1) && (qx <= 96) && (qy >= 1) && (qy <= 96);
            int gr = qx - 1, gc = qy - 1;
            int wr = gr - (hr - 2), wcl = gc - (wc - 3);
            bool inwin = ((unsigned)wr < (unsigned)NWR) && ((unsigned)wcl < (unsigned)NWC);
            unsigned short idxv; float gvf;
            if (inwin) {
                idxv = (unsigned short)(wr * NWC + wcl);
                gvf = gs4[c4] * modv;
            } else if (!valid) {
                idxv = 0; gvf = 0.f;
            } else {
                int s = atomicAdd(&s_cnt, 1);
                int gidx = gr * 96 + gc;
                if (s < NSLOTS) {
                    int ps = WINPX + s;
                    #pragma unroll
                    for (int ch = 0; ch < 8; ++ch) {
                        uint4 v = *(const uint4*)(xtb + (size_t)gidx * 64 + ch * 8);
                        *(uint4*)(s_win + (size_t)ps * 128 + ((ch ^ (ps & 7)) * 16)) = v;
                    }
                    idxv = (unsigned short)ps;
                } else {
                    idxv = (unsigned short)(0x8000u | (unsigned)gidx);
                }
                gvf = gs4[c4] * modv;
            }
            si[c4] = idxv;
            hg[c4] = __half_as_ushort(__float2half_rn(gvf));
        }
        uint4 mw4;
        mw4.x = si[0] | ((unsigned)si[1] << 16);
        mw4.y = si[2] | ((unsigned)si[3] << 16);
        mw4.z = hg[0] | ((unsigned)hg[1] << 16);
        mw4.w = hg[2] | ((unsigned)hg[3] << 16);
        *(uint4*)(s_meta + ((size_t)px * 9 + n) * 16) = mw4;
    };
    meta_one(tid,       ox0, oy0, mv0);
    meta_one(tid + 384, ox1, oy1, mv1);
    if (has2) meta_one(tid + 768, ox2, oy2, mv2);
    __syncthreads();

    // ---- phase 3: wave = 16 px x 64 o-channels; single gather per corner ----
    int px3 = w * 16 + col;
    floatx4 acc[4];
    #pragma unroll
    for (int mt = 0; mt < 4; ++mt) acc[mt] = (floatx4){0.f, 0.f, 0.f, 0.f};

    int qk0 = quad * 16, qk1 = quad * 16 + 64;

    #pragma unroll
    for (int n = 0; n < 9; ++n) {
        uint4 mu = *(const uint4*)(s_meta + ((size_t)px3 * 9 + n) * 16);
        unsigned i0 = mu.x & 0xFFFFu, i1 = mu.x >> 16;
        unsigned i2 = mu.y & 0xFFFFu, i3 = mu.y >> 16;
        int pm0 = (i0 & 0x8000u) ? 0 : (int)i0;
        int pm1 = (i1 & 0x8000u) ? 0 : (int)i1;
        int pm2 = (i2 & 0x8000u) ? 0 : (int)i2;
        int pm3 = (i3 & 0x8000u) ? 0 : (int)i3;
        int b0 = pm0 << 7, s0 = (pm0 & 7) << 4;
        int b1 = pm1 << 7, s1 = (pm1 & 7) << 4;
        int b2 = pm2 << 7, s2 = (pm2 & 7) << 4;
        int b3 = pm3 << 7, s3 = (pm3 & 7) << 4;
        uint4 cA0 = *(const uint4*)(s_win + b0 + (qk0 ^ s0));
        uint4 cA1 = *(const uint4*)(s_win + b1 + (qk0 ^ s1));
        uint4 cA2 = *(const uint4*)(s_win + b2 + (qk0 ^ s2));
        uint4 cA3 = *(const uint4*)(s_win + b3 + (qk0 ^ s3));
        uint4 cB0 = *(const uint4*)(s_win + b0 + (qk1 ^ s0));
        uint4 cB1 = *(const uint4*)(s_win + b1 + (qk1 ^ s1));
        uint4 cB2 = *(const uint4*)(s_win + b2 + (qk1 ^ s2));
        uint4 cB3 = *(const uint4*)(s_win + b3 + (qk1 ^ s3));
        if (__any((int)((i0 | i1 | i2 | i3) & 0x8000u))) {
            if (i0 & 0x8000u) { size_t ga = (size_t)(i0 & 0x3FFFu) * 64 + quad * 8;
                cA0 = *(const uint4*)(xtb + ga); cB0 = *(const uint4*)(xtb + ga + 32); }
            if (i1 & 0x8000u) { size_t ga = (size_t)(i1 & 0x3FFFu) * 64 + quad * 8;
                cA1 = *(const uint4*)(xtb + ga); cB1 = *(const uint4*)(xtb + ga + 32); }
            if (i2 & 0x8000u) { size_t ga = (size_t)(i2 & 0x3FFFu) * 64 + quad * 8;
                cA2 = *(const uint4*)(xtb + ga); cB2 = *(const uint4*)(xtb + ga + 32); }
            if (i3 & 0x8000u) { size_t ga = (size_t)(i3 & 0x3FFFu) * 64 + quad * 8;
                cA3 = *(const uint4*)(xtb + ga); cB3 = *(const uint4*)(xtb + ga + 32); }
        }
        unsigned gl0 = (mu.z & 0xFFFFu) | (mu.z << 16);
        unsigned gl1 = (mu.z >> 16) | (mu.z & 0xFFFF0000u);
        unsigned gl2 = (mu.w & 0xFFFFu) | (mu.w << 16);
        unsigned gl3 = (mu.w >> 16) | (mu.w & 0xFFFF0000u);
        halfx8 g0 = splat8(gl0), g1 = splat8(gl1), g2 = splat8(gl2), g3 = splat8(gl3);
        halfx8 vA = uph8(cA0) * g0;
        vA += uph8(cA1) * g1; vA += uph8(cA2) * g2; vA += uph8(cA3) * g3;
        halfx8 vB = uph8(cB0) * g0;
        vB += uph8(cB1) * g1; vB += uph8(cB2) * g2; vB += uph8(cB3) * g3;
        __builtin_amdgcn_s_setprio(1);
        #pragma unroll
        for (int mt = 0; mt < 4; ++mt) {
            halfx8 afA = *(const halfx8*)(wfm + ((size_t)((n * 2 + 0) * 4 + mt) * 64 + lane) * 8);
            halfx8 afB = *(const halfx8*)(wfm + ((size_t)((n * 2 + 1) * 4 + mt) * 64 + lane) * 8);
            acc[mt] = __builtin_amdgcn_mfma_f32_16x16x32_f16(afA, vA, acc[mt], 0, 0, 0);
            acc[mt] = __builtin_amdgcn_mfma_f32_16x16x32_f16(afB, vB, acc[mt], 0, 0, 0);
        }
        __builtin_amdgcn_s_setprio(0);
    }

    // ---- epilogue: wave writes 16 px x 64 o ----
    int sp = (hr + (w >> 1)) * 96 + wc + (w & 1) * 16 + col;
    #pragma unroll
    for (int mt = 0; mt < 4; ++mt) {
        float4 cb4 = *(const float4*)&convb[mt * 16 + quad * 4];
        #pragma unroll
        for (int r = 0; r < 4; ++r) {
            int o = mt * 16 + quad * 4 + r;
            float bias = (r == 0) ? cb4.x : (r == 1) ? cb4.y : (r == 2) ? cb4.z : cb4.w;
            out[(size_t)(bb * 64 + o) * HW_ + sp] = acc[mt][r] + bias;
        }
    }
}

// ---------------------------------------------------------------------------
extern "C" void kernel_launch(void* const* d_in, const int* in_sizes, int n_in,
                              void* d_out, int out_size, void* d_ws, size_t ws_size,
                              hipStream_t stream) {
    const float* x     = (const float*)d_in[0];
    const float* offw  = (const float*)d_in[1];
    const float* offb  = (const float*)d_in[2];
    const float* mw    = (const float*)d_in[3];
    const float* mb    = (const float*)d_in[4];
    const float* convw = (const float*)d_in[5];
    const float* convb = (const float*)d_in[6];
    char* ws = (char*)d_ws;
    unsigned short* xt16 = (unsigned short*)(ws + XT_OFF);
    unsigned short* wfm  = (unsigned short*)(ws + WFM_OFF);
    unsigned short* wfo  = (unsigned short*)(ws + WFO_OFF);
    unsigned short* wz   = (unsigned short*)(ws + WZ_OFF);
    float* out = (float*)d_out;

    k_transpose<<<dim3(1152 + 28), dim3(256), 0, stream>>>(x, xt16, offw, mw, convw, wfm, wfo, wz);
    k_fused    <<<dim3(768),       dim3(384), 0, stream>>>(xt16, wfo, wfm, offb, mb, convb, wz, out);
}

// Round 13
// 109.035 us; speedup vs baseline: 2.0052x; 1.0980x over previous
//
#include <hip/hip_runtime.h>
#include <hip/hip_fp16.h>
#include <cstddef>

#define B_   8
#define H_   96
#define W_   96
#define HW_  9216
#define PIX_ 73728

// LDS window geometry: rows hr-2..hr+4 (7), cols wc-3..wc+34 (38)
#define NWR    7
#define NWC    38
#define WINPX  266
#define NSLOTS 19

typedef __attribute__((ext_vector_type(8))) _Float16 halfx8;
typedef __attribute__((ext_vector_type(2))) __fp16 fp16x2_raw;
typedef __attribute__((ext_vector_type(4))) float floatx4;

// ws layout (byte offsets)
#define XT_OFF   0                          // fp16 NHWC x: PIX*64*2
#define WFM_OFF  (XT_OFF + PIX_*64*2)       // main W frags: 18*4*64*8 fp16
#define WFO_OFF  (WFM_OFF + 18*4*64*8*2)    // offs W frags: 18*2*64*8 fp16
#define WZ_OFF   (WFO_OFF + 18*2*64*8*2)    // 128B zero page

__device__ __forceinline__ unsigned pk2h(float a, float b) {
    fp16x2_raw h = __builtin_amdgcn_cvt_pkrtz(a, b);
    union { fp16x2_raw h2; unsigned u; } t; t.h2 = h; return t.u;
}
__device__ __forceinline__ halfx8 uph8(uint4 u) {
    union { uint4 u4; halfx8 h; } t; t.u4 = u; return t.h;
}
__device__ __forceinline__ halfx8 splat8(unsigned d) {
    union { unsigned u[4]; halfx8 h; } t;
    t.u[0] = d; t.u[1] = d; t.u[2] = d; t.u[3] = d; return t.h;
}
__device__ __forceinline__ void async_ld16(const void* g, void* l) {
    __builtin_amdgcn_global_load_lds((const __attribute__((address_space(1))) void*)g,
                                     (__attribute__((address_space(3))) void*)l,
                                     16, 0, 0);
}

// ---------------------------------------------------------------------------
// Weight prep item (shared helper)
__device__ __forceinline__ void prep_weight_item(int g,
                                                 const float* __restrict__ offw,
                                                 const float* __restrict__ mw,
                                                 const float* __restrict__ convw,
                                                 unsigned short* __restrict__ wfm,
                                                 unsigned short* __restrict__ wfo) {
    if (g < 4608) {
        int lane = g & 63, mtks = g >> 6;
        int mt = mtks & 3, ks = mtks >> 2;
        int o = mt * 16 + (lane & 15), quad = lane >> 4;
        float v[8];
        #pragma unroll
        for (int j = 0; j < 8; ++j) {
            int k = ks * 32 + quad * 8 + j;
            int t = k / 64, c = k % 64;
            v[j] = convw[(size_t)(o * 64 + c) * 9 + t];
        }
        uint4 pk;
        pk.x = pk2h(v[0], v[1]); pk.y = pk2h(v[2], v[3]);
        pk.z = pk2h(v[4], v[5]); pk.w = pk2h(v[6], v[7]);
        *(uint4*)(wfm + (size_t)g * 8) = pk;
    } else if (g < 4608 + 2304) {
        int g2 = g - 4608;
        int lane = g2 & 63, mtks = g2 >> 6;
        int mt = mtks & 1, ks = mtks >> 1;
        int m = mt * 16 + (lane & 15), quad = lane >> 4;
        float v[8];
        #pragma unroll
        for (int j = 0; j < 8; ++j) {
            int k = ks * 32 + quad * 8 + j;
            int t = k / 64, c = k % 64;
            float f = 0.f;
            if (m < 18)      f = offw[(size_t)(m * 64 + c) * 9 + t];
            else if (m < 27) f = mw[(size_t)((m - 18) * 64 + c) * 9 + t];
            v[j] = f;
        }
        uint4 pk;
        pk.x = pk2h(v[0], v[1]); pk.y = pk2h(v[2], v[3]);
        pk.z = pk2h(v[4], v[5]); pk.w = pk2h(v[6], v[7]);
        *(uint4*)(wfo + (size_t)g2 * 8) = pk;
    }
}

// ---------------------------------------------------------------------------
// NCHW f32 -> NHWC fp16 transpose via LDS tile; tail blocks pack weights.
__global__ __launch_bounds__(256) void k_transpose(const float* __restrict__ x,
                                                   unsigned short* __restrict__ xt,
                                                   const float* __restrict__ offw,
                                                   const float* __restrict__ mw,
                                                   const float* __restrict__ convw,
                                                   unsigned short* __restrict__ wfm,
                                                   unsigned short* __restrict__ wfo,
                                                   unsigned short* __restrict__ wz) {
    if (blockIdx.x >= 1152) {
        int g = (blockIdx.x - 1152) * 256 + threadIdx.x;
        if (g < 6912) prep_weight_item(g, offw, mw, convw, wfm, wfo);
        else if (g < 6920) {
            uint4 z = make_uint4(0, 0, 0, 0);
            *(uint4*)(wz + (size_t)(g - 6912) * 8) = z;
        }
        return;
    }
    __shared__ float tile[64 * 65];
    int bb  = blockIdx.x / 144;
    int sp0 = (blockIdx.x % 144) * 64;
    int t = threadIdx.x;
    int s4 = (t & 15) * 4, cq = t >> 4;
    #pragma unroll
    for (int i = 0; i < 4; ++i) {
        int c = cq + 16 * i;
        float4 v = *(const float4*)&x[(size_t)(bb * 64 + c) * HW_ + sp0 + s4];
        tile[c * 65 + s4 + 0] = v.x;
        tile[c * 65 + s4 + 1] = v.y;
        tile[c * 65 + s4 + 2] = v.z;
        tile[c * 65 + s4 + 3] = v.w;
    }
    __syncthreads();
    int c8 = t & 7, sgrp = t >> 3;
    #pragma unroll
    for (int i = 0; i < 2; ++i) {
        int s2 = i * 32 + sgrp;
        uint4 pk;
        pk.x = pk2h(tile[(c8 * 8 + 0) * 65 + s2], tile[(c8 * 8 + 1) * 65 + s2]);
        pk.y = pk2h(tile[(c8 * 8 + 2) * 65 + s2], tile[(c8 * 8 + 3) * 65 + s2]);
        pk.z = pk2h(tile[(c8 * 8 + 4) * 65 + s2], tile[(c8 * 8 + 5) * 65 + s2]);
        pk.w = pk2h(tile[(c8 * 8 + 6) * 65 + s2], tile[(c8 * 8 + 7) * 65 + s2]);
        *(uint4*)(xt + (size_t)(bb * HW_ + sp0 + s2) * 64 + c8 * 8) = pk;
    }
}

// ---------------------------------------------------------------------------
// Fused kernel (R9 exact). Block = 384 thr = 6 waves, owns 96 px (3 rows x
// 32 cols). 768 blocks = 3 blocks/CU x 256 CU. 7x38 window DMA'd to LDS;
// s_off aliased onto s_meta; wave = 16 px x 64 o-channels. NO setprio
// (measured -10 us: all-wave priority raise starves staging DMA, R12).
__global__ __launch_bounds__(384, 4) void k_fused(const unsigned short* __restrict__ xt,
                                                  const unsigned short* __restrict__ wfo,
                                                  const unsigned short* __restrict__ wfm,
                                                  const float* __restrict__ offb,
                                                  const float* __restrict__ mb,
                                                  const float* __restrict__ convb,
                                                  const unsigned short* __restrict__ wz,
                                                  float* __restrict__ out) {
    __shared__ __align__(16) unsigned char s_win[(WINPX + NSLOTS) * 128];  // 36480 B
    __shared__ __align__(16) unsigned char s_u[96 * 9 * 16];               // 13824 B union
    __shared__ int s_cnt;
    float* s_off = (float*)s_u;
    unsigned char* s_meta = s_u;

    int tid = threadIdx.x;
    int w = tid >> 6, lane = tid & 63, col = lane & 15, quad = lane >> 4;
    // XCD-aware swizzle: each XCD owns one batch region (768 = 8 x 96)
    int blk = (blockIdx.x & 7) * 96 + (blockIdx.x >> 3);
    int bb  = blk / 96;
    int rem = blk % 96;
    int hr  = (rem / 3) * 3;
    int wc  = (rem % 3) * 32;
    const unsigned short* xtb = xt + (size_t)bb * HW_ * 64;

    // ---- stage window: direct-to-LDS DMA, source pre-swizzled; OOB -> zeros ----
    if (tid == 0) s_cnt = 0;
    {
        int p0  = lane >> 3;
        int cgx = (lane & 7) ^ p0;
        const unsigned short* wzp = wz + cgx * 8;
        for (int i = w; i < 34; i += 6) {
            int p = i * 8 + p0;
            int wr = p / NWC, wcl = p - wr * NWC;
            int gr = hr - 2 + wr, gc = wc - 3 + wcl;
            bool ok = (p < WINPX) && ((unsigned)gr < 96u) && ((unsigned)gc < 96u);
            const unsigned short* src = ok ? (xtb + ((size_t)(gr * 96 + gc) * 64 + cgx * 8)) : wzp;
            async_ld16(src, s_win + i * 1024);
        }
    }
    __syncthreads();

    // ---- phase 1: offset/mod conv GEMM (B from LDS window) ----
    floatx4 aoff0 = (floatx4){0.f, 0.f, 0.f, 0.f};
    floatx4 aoff1 = (floatx4){0.f, 0.f, 0.f, 0.f};
    {
        int wr_base = 2 + (w >> 1);
        int wc_base = 3 + (w & 1) * 16 + col;
        #pragma unroll
        for (int t = 0; t < 9; ++t) {
            int dh = t / 3 - 1, dw = t % 3 - 1;
            int p = (wr_base + dh) * NWC + (wc_base + dw);
            int pb = p << 7, psw = (p & 7) << 4;
            #pragma unroll
            for (int ksl = 0; ksl < 2; ++ksl) {
                int ks = t * 2 + ksl;
                halfx8 a0 = *(const halfx8*)(wfo + ((size_t)(ks * 2 + 0) * 64 + lane) * 8);
                halfx8 a1 = *(const halfx8*)(wfo + ((size_t)(ks * 2 + 1) * 64 + lane) * 8);
                uint4 bvu = *(const uint4*)(s_win + pb + ((quad * 16 + ksl * 64) ^ psw));
                halfx8 bv = uph8(bvu);
                aoff0 = __builtin_amdgcn_mfma_f32_16x16x32_f16(a0, bv, aoff0, 0, 0, 0);
                aoff1 = __builtin_amdgcn_mfma_f32_16x16x32_f16(a1, bv, aoff1, 0, 0, 0);
            }
        }
    }
    #pragma unroll
    for (int r = 0; r < 4; ++r) {
        s_off[(quad * 4 + r) * 98 + (w * 16 + col)] = aoff0[r];
        int m = 16 + quad * 4 + r;
        if (m < 27) s_off[m * 98 + (w * 16 + col)] = aoff1[r];
    }
    __syncthreads();

    // ---- phase 2a: read s_off (+bias) into static registers (864 items) ----
    float ox0, oy0, mv0, ox1, oy1, mv1, ox2 = 0.f, oy2 = 0.f, mv2 = 0.f;
    bool has2 = tid < 96;
    {
        int px = tid % 96, n = tid / 96;
        ox0 = s_off[n * 98 + px]        + offb[n];
        oy0 = s_off[(9 + n) * 98 + px]  + offb[9 + n];
        mv0 = s_off[(18 + n) * 98 + px] + mb[n];
    }
    {
        int id = tid + 384;
        int px = id % 96, n = id / 96;
        ox1 = s_off[n * 98 + px]        + offb[n];
        oy1 = s_off[(9 + n) * 98 + px]  + offb[9 + n];
        mv1 = s_off[(18 + n) * 98 + px] + mb[n];
    }
    if (has2) {
        int id = tid + 768;
        int px = id % 96, n = id / 96;
        ox2 = s_off[n * 98 + px]        + offb[n];
        oy2 = s_off[(9 + n) * 98 + px]  + offb[9 + n];
        mv2 = s_off[(18 + n) * 98 + px] + mb[n];
    }
    __syncthreads();   // s_off fully read; s_u becomes s_meta

    // ---- phase 2b: bilinear metadata ----
    auto meta_one = [&](int id, float ox, float oy, float mv) {
        int px = id % 96, n = id / 96;
        float modv = 1.f / (1.f + __expf(-mv));
        int prow = hr + (px >> 5), pcol = wc + (px & 31);
        float pxx = ox + (float)(prow + 1) + (float)(n / 3 - 1);
        float pyy = oy + (float)(pcol + 1) + (float)(n % 3 - 1);
        float flx = floorf(pxx), fly = floorf(pyy);
        float tlxf = fminf(fmaxf(flx,       0.f), 97.f);
        float tlyf = fminf(fmaxf(fly,       0.f), 97.f);
        float brxf = fminf(fmaxf(flx + 1.f, 0.f), 97.f);
        float bryf = fminf(fmaxf(fly + 1.f, 0.f), 97.f);
        float pcx  = fminf(fmaxf(pxx, 0.f), 97.f);
        float pcy  = fminf(fmaxf(pyy, 0.f), 97.f);
        float gx0 = 1.f + tlxf - pcx;
        float gx1 = 1.f - (brxf - pcx);
        float gy0 = 1.f + tlyf - pcy;
        float gy1 = 1.f - (bryf - pcy);
        int tlx = (int)tlxf, tly = (int)tlyf, brx = (int)brxf, bry = (int)bryf;
        int   qxs[4] = {tlx, tlx, brx, brx};
        int   qys[4] = {tly, bry, tly, bry};
        float gs4[4] = {gx0 * gy0, gx0 * gy1, gx1 * gy0, gx1 * gy1};
        unsigned short si[4]; unsigned short hg[4];
        #pragma unroll
        for (int c4 = 0; c4 < 4; ++c4) {
            int qx = qxs[c4], qy = qys[c4];
            bool valid = (qx >= 1) && (qx <= 96) && (qy >= 1) && (qy <= 96);
            int gr = qx - 1, gc = qy - 1;
            int wr = gr - (hr - 2), wcl = gc - (wc - 3);
            bool inwin = ((unsigned)wr < (unsigned)NWR) && ((unsigned)wcl < (unsigned)NWC);
            unsigned short idxv; float gvf;
            if (inwin) {
                idxv = (unsigned short)(wr * NWC + wcl);
                gvf = gs4[c4] * modv;
            } else if (!valid) {
                idxv = 0; gvf = 0.f;
            } else {
                int s = atomicAdd(&s_cnt, 1);
                int gidx = gr * 96 + gc;
                if (s < NSLOTS) {
                    int ps = WINPX + s;
                    #pragma unroll
                    for (int ch = 0; ch < 8; ++ch) {
                        uint4 v = *(const uint4*)(xtb + (size_t)gidx * 64 + ch * 8);
                        *(uint4*)(s_win + (size_t)ps * 128 + ((ch ^ (ps & 7)) * 16)) = v;
                    }
                    idxv = (unsigned short)ps;
                } else {
                    idxv = (unsigned short)(0x8000u | (unsigned)gidx);
                }
                gvf = gs4[c4] * modv;
            }
            si[c4] = idxv;
            hg[c4] = __half_as_ushort(__float2half_rn(gvf));
        }
        uint4 mw4;
        mw4.x = si[0] | ((unsigned)si[1] << 16);
        mw4.y = si[2] | ((unsigned)si[3] << 16);
        mw4.z = hg[0] | ((unsigned)hg[1] << 16);
        mw4.w = hg[2] | ((unsigned)hg[3] << 16);
        *(uint4*)(s_meta + ((size_t)px * 9 + n) * 16) = mw4;
    };
    meta_one(tid,       ox0, oy0, mv0);
    meta_one(tid + 384, ox1, oy1, mv1);
    if (has2) meta_one(tid + 768, ox2, oy2, mv2);
    __syncthreads();

    // ---- phase 3: wave = 16 px x 64 o-channels; single gather per corner ----
    int px3 = w * 16 + col;
    floatx4 acc[4];
    #pragma unroll
    for (int mt = 0; mt < 4; ++mt) acc[mt] = (floatx4){0.f, 0.f, 0.f, 0.f};

    int qk0 = quad * 16, qk1 = quad * 16 + 64;

    #pragma unroll
    for (int n = 0; n < 9; ++n) {
        uint4 mu = *(const uint4*)(s_meta + ((size_t)px3 * 9 + n) * 16);
        unsigned i0 = mu.x & 0xFFFFu, i1 = mu.x >> 16;
        unsigned i2 = mu.y & 0xFFFFu, i3 = mu.y >> 16;
        int pm0 = (i0 & 0x8000u) ? 0 : (int)i0;
        int pm1 = (i1 & 0x8000u) ? 0 : (int)i1;
        int pm2 = (i2 & 0x8000u) ? 0 : (int)i2;
        int pm3 = (i3 & 0x8000u) ? 0 : (int)i3;
        int b0 = pm0 << 7, s0 = (pm0 & 7) << 4;
        int b1 = pm1 << 7, s1 = (pm1 & 7) << 4;
        int b2 = pm2 << 7, s2 = (pm2 & 7) << 4;
        int b3 = pm3 << 7, s3 = (pm3 & 7) << 4;
        uint4 cA0 = *(const uint4*)(s_win + b0 + (qk0 ^ s0));
        uint4 cA1 = *(const uint4*)(s_win + b1 + (qk0 ^ s1));
        uint4 cA2 = *(const uint4*)(s_win + b2 + (qk0 ^ s2));
        uint4 cA3 = *(const uint4*)(s_win + b3 + (qk0 ^ s3));
        uint4 cB0 = *(const uint4*)(s_win + b0 + (qk1 ^ s0));
        uint4 cB1 = *(const uint4*)(s_win + b1 + (qk1 ^ s1));
        uint4 cB2 = *(const uint4*)(s_win + b2 + (qk1 ^ s2));
        uint4 cB3 = *(const uint4*)(s_win + b3 + (qk1 ^ s3));
        if (__any((int)((i0 | i1 | i2 | i3) & 0x8000u))) {
            if (i0 & 0x8000u) { size_t ga = (size_t)(i0 & 0x3FFFu) * 64 + quad * 8;
                cA0 = *(const uint4*)(xtb + ga); cB0 = *(const uint4*)(xtb + ga + 32); }
            if (i1 & 0x8000u) { size_t ga = (size_t)(i1 & 0x3FFFu) * 64 + quad * 8;
                cA1 = *(const uint4*)(xtb + ga); cB1 = *(const uint4*)(xtb + ga + 32); }
            if (i2 & 0x8000u) { size_t ga = (size_t)(i2 & 0x3FFFu) * 64 + quad * 8;
                cA2 = *(const uint4*)(xtb + ga); cB2 = *(const uint4*)(xtb + ga + 32); }
            if (i3 & 0x8000u) { size_t ga = (size_t)(i3 & 0x3FFFu) * 64 + quad * 8;
                cA3 = *(const uint4*)(xtb + ga); cB3 = *(const uint4*)(xtb + ga + 32); }
        }
        unsigned gl0 = (mu.z & 0xFFFFu) | (mu.z << 16);
        unsigned gl1 = (mu.z >> 16) | (mu.z & 0xFFFF0000u);
        unsigned gl2 = (mu.w & 0xFFFFu) | (mu.w << 16);
        unsigned gl3 = (mu.w >> 16) | (mu.w & 0xFFFF0000u);
        halfx8 g0 = splat8(gl0), g1 = splat8(gl1), g2 = splat8(gl2), g3 = splat8(gl3);
        halfx8 vA = uph8(cA0) * g0;
        vA += uph8(cA1) * g1; vA += uph8(cA2) * g2; vA += uph8(cA3) * g3;
        halfx8 vB = uph8(cB0) * g0;
        vB += uph8(cB1) * g1; vB += uph8(cB2) * g2; vB += uph8(cB3) * g3;
        #pragma unroll
        for (int mt = 0; mt < 4; ++mt) {
            halfx8 afA = *(const halfx8*)(wfm + ((size_t)((n * 2 + 0) * 4 + mt) * 64 + lane) * 8);
            halfx8 afB = *(const halfx8*)(wfm + ((size_t)((n * 2 + 1) * 4 + mt) * 64 + lane) * 8);
            acc[mt] = __builtin_amdgcn_mfma_f32_16x16x32_f16(afA, vA, acc[mt], 0, 0, 0);
            acc[mt] = __builtin_amdgcn_mfma_f32_16x16x32_f16(afB, vB, acc[mt], 0, 0, 0);
        }
    }

    // ---- epilogue: wave writes 16 px x 64 o ----
    int sp = (hr + (w >> 1)) * 96 + wc + (w & 1) * 16 + col;
    #pragma unroll
    for (int mt = 0; mt < 4; ++mt) {
        float4 cb4 = *(const float4*)&convb[mt * 16 + quad * 4];
        #pragma unroll
        for (int r = 0; r < 4; ++r) {
            int o = mt * 16 + quad * 4 + r;
            float bias = (r == 0) ? cb4.x : (r == 1) ? cb4.y : (r == 2) ? cb4.z : cb4.w;
            out[(size_t)(bb * 64 + o) * HW_ + sp] = acc[mt][r] + bias;
        }
    }
}

// ---------------------------------------------------------------------------
extern "C" void kernel_launch(void* const* d_in, const int* in_sizes, int n_in,
                              void* d_out, int out_size, void* d_ws, size_t ws_size,
                              hipStream_t stream) {
    const float* x     = (const float*)d_in[0];
    const float* offw  = (const float*)d_in[1];
    const float* offb  = (const float*)d_in[2];
    const float* mw    = (const float*)d_in[3];
    const float* mb    = (const float*)d_in[4];
    const float* convw = (const float*)d_in[5];
    const float* convb = (const float*)d_in[6];
    char* ws = (char*)d_ws;
    unsigned short* xt16 = (unsigned short*)(ws + XT_OFF);
    unsigned short* wfm  = (unsigned short*)(ws + WFM_OFF);
    unsigned short* wfo  = (unsigned short*)(ws + WFO_OFF);
    unsigned short* wz   = (unsigned short*)(ws + WZ_OFF);
    float* out = (float*)d_out;

    k_transpose<<<dim3(1152 + 28), dim3(256), 0, stream>>>(x, xt16, offw, mw, convw, wfm, wfo, wz);
    k_fused    <<<dim3(768),       dim3(384), 0, stream>>>(xt16, wfo, wfm, offb, mb, convb, wz, out);
}